// Round 1
// baseline (234.607 us; speedup 1.0000x reference)
//
#include <hip/hip_runtime.h>
#include <math.h>

#ifndef M_PI
#define M_PI 3.14159265358979323846
#endif

#define NWIN   400
#define NSHIFT 160
#define NMELS  80
#define NBIN   256
#define NFRM   998
#define WLEN   160000
#define FPB    4
#define BPB    250          // ceil(998/4) frame-blocks per batch
#define EPSV   1.1920929e-07f

// 4-sample Goertzel step, roles rotated so no register moves are needed.
// Invariant on entry: s1 = s_{n-1}, s2 = s_{n-2}; on exit same with n += 4.
__device__ __forceinline__ void gstep4f(float c, float& s1, float& s2, float4 y)
{
    float a = fmaf(c, s1, y.x - s2);
    float b = fmaf(c, a,  y.y - s1);
    s2      = fmaf(c, b,  y.z - a);
    s1      = fmaf(c, s2, y.w - b);
}

__device__ __forceinline__ void gstep4d(double c, double& s1, double& s2, float4 y)
{
    double a = fma(c, s1, (double)y.x - s2);
    double b = fma(c, a,  (double)y.y - s1);
    s2       = fma(c, b,  (double)y.z - a);
    s1       = fma(c, s2, (double)y.w - b);
}

__global__ __launch_bounds__(320)
void fbank_kernel(const float* __restrict__ wav, float* __restrict__ out)
{
    __shared__ __align__(16) float xraw[FPB][NWIN];    // raw frame samples
    __shared__ __align__(16) float ybuf[FPB][NWIN];    // windowed frames
    __shared__ __align__(16) float pbuf[FPB][NBIN];    // power spectra
    __shared__ __align__(16) float prisky[FPB][32];    // f64-recomputed risky bins
    __shared__ __align__(16) float ubuf[NBIN];         // mel-scale coordinate of each bin
    __shared__ __align__(16) float res[NMELS * FPB];   // logmel, [mel][frame-slot]

    const int tid  = threadIdx.x;
    const int lane = tid & 63;
    const int wv   = tid >> 6;             // 0..3 = frame waves, 4 = risky f64 wave
    const int bb   = blockIdx.x / BPB;
    const int f0   = (blockIdx.x % BPB) * FPB;

    const float ML = 1127.0f * logf(1.0f + 20.0f / 700.0f);
    const float MH = 1127.0f * logf(1.0f + 8000.0f / 700.0f);
    const float DD = (MH - ML) / (float)(NMELS + 1);

    // ---- phase 1: preprocess frames (waves 0..3) / build mel table (wave 4) ----
    if (wv == 4) {
        #pragma unroll
        for (int r = 0; r < 4; ++r) {
            int b = lane + 64 * r;
            float freq = (float)b * (16000.0f / 512.0f);
            float mel  = 1127.0f * logf(1.0f + freq * (1.0f / 700.0f));
            ubuf[b] = (mel - ML) / DD;
        }
    } else if (f0 + wv < NFRM) {
        const float* xp = wav + (size_t)bb * WLEN + (size_t)(f0 + wv) * NSHIFT;
        float s = 0.0f;
        #pragma unroll
        for (int t = 0; t < 7; ++t) {
            int n = lane + 64 * t;
            if (n < NWIN) { float v = xp[n]; xraw[wv][n] = v; s += v; }
        }
        #pragma unroll
        for (int off = 32; off > 0; off >>= 1) s += __shfl_xor(s, off, 64);
        const float mu = s * (1.0f / (float)NWIN);
        const float CW = (float)(2.0 * M_PI / 399.0);
        #pragma unroll
        for (int t = 0; t < 7; ++t) {
            int n = lane + 64 * t;
            if (n < NWIN) {
                float xn = xraw[wv][n];
                float xm = (n == 0) ? xn : xraw[wv][n - 1];
                float y  = (xn - mu) - 0.97f * (xm - mu);
                // Povey window; clamp guards cosf(2*pi) rounding above 1 -> powf(neg) NaN
                float a  = fmaxf(0.5f - 0.5f * cosf((float)n * CW), 0.0f);
                ybuf[wv][n] = y * powf(a, 0.85f);
            }
        }
    }
    __syncthreads();

    // ---- phase 2: Goertzel DFT power spectrum ----
    if (wv < 4) {
        if (f0 + wv < NFRM) {
            const int k0 = 4 * lane;                 // bins 4l..4l+3
            const float cs = (float)(M_PI / 256.0);  // omega_k = pi*k/256
            float c0 = 2.0f * cosf((float)(k0 + 0) * cs);
            float c1 = 2.0f * cosf((float)(k0 + 1) * cs);
            float c2 = 2.0f * cosf((float)(k0 + 2) * cs);
            float c3 = 2.0f * cosf((float)(k0 + 3) * cs);
            float s10 = 0, s20 = 0, s11 = 0, s21 = 0;
            float s12 = 0, s22 = 0, s13 = 0, s23 = 0;
            for (int n = 0; n < NWIN; n += 4) {
                float4 y = *(const float4*)&ybuf[wv][n];   // broadcast ds_read_b128
                gstep4f(c0, s10, s20, y);
                gstep4f(c1, s11, s21, y);
                gstep4f(c2, s12, s22, y);
                gstep4f(c3, s13, s23, y);
            }
            float4 pw;   // |X|^2 = s1^2 + s2^2 - c*s1*s2
            pw.x = fmaf(s10, s10, fmaf(s20, s20, -c0 * s10 * s20));
            pw.y = fmaf(s11, s11, fmaf(s21, s21, -c1 * s11 * s21));
            pw.z = fmaf(s12, s12, fmaf(s22, s22, -c2 * s12 * s22));
            pw.w = fmaf(s13, s13, fmaf(s23, s23, -c3 * s13 * s23));
            *(float4*)&pbuf[wv][k0] = pw;
        }
    } else {
        // wave 4: bins k in {1..15, 241..255} have 1/sin^2(w) Goertzel error
        // amplification -> redo in fp64 (half-rate f64 ~= one frame-wave's cost)
        const int slot = lane >> 4;        // frame slot 0..3
        const int i    = lane & 15;
        const int ia   = (i < 15) ? i : 14;   // lane 15 of each group duplicates, no write
        if (f0 + slot < NFRM) {
            const int kA = 1 + ia, kB = 241 + ia;
            const double cA = 2.0 * cos(M_PI * (double)kA / 256.0);
            const double cB = 2.0 * cos(M_PI * (double)kB / 256.0);
            double a1 = 0, a2 = 0, b1 = 0, b2 = 0;
            for (int n = 0; n < NWIN; n += 4) {
                float4 y = *(const float4*)&ybuf[slot][n];
                gstep4d(cA, a1, a2, y);
                gstep4d(cB, b1, b2, y);
            }
            if (i < 15) {
                prisky[slot][ia]      = (float)(a1 * a1 + a2 * a2 - cA * a1 * a2);
                prisky[slot][15 + ia] = (float)(b1 * b1 + b2 * b2 - cB * b1 * b2);
            }
        }
    }
    __syncthreads();

    // ---- phase 3: splice risky bins, mel triangles, log ----
    if (wv < 4 && f0 + wv < NFRM) {
        if (lane < 30) {
            int b = (lane < 15) ? (1 + lane) : (241 + lane - 15);
            pbuf[wv][b] = prisky[wv][lane];   // same-wave LDS ordering covers the read below
        }
        #pragma unroll
        for (int round = 0; round < 2; ++round) {
            int j = lane + 64 * round;
            if (j < NMELS) {
                // support of triangle j in bin space: u in (j, j+2)
                float mlo  = ML + (float)j * DD;
                float mhi  = ML + (float)(j + 2) * DD;
                float bflo = 22.4f * (expf(mlo * (1.0f / 1127.0f)) - 1.0f);  // 700/31.25
                float bfhi = 22.4f * (expf(mhi * (1.0f / 1127.0f)) - 1.0f);
                int blo = max(1,   (int)bflo);          // +-1 slack is weight-clamped
                int bhi = min(255, (int)bfhi + 1);
                float jf  = (float)j;
                float jf2 = (float)(j + 2);
                float acc = 0.0f;
                for (int b = blo; b <= bhi; ++b) {
                    float u   = ubuf[b];
                    float wgt = fmaxf(0.0f, fminf(u - jf, jf2 - u));
                    acc = fmaf(wgt, pbuf[wv][b], acc);
                }
                res[j * FPB + wv] = logf(fmaxf(acc, EPSV));
            }
        }
    }
    __syncthreads();

    // ---- phase 4: transposed output write, float2 bursts ----
    const int nval = min(FPB, NFRM - f0);      // 4, or 2 in the tail block
    if (tid < NMELS * 2) {
        int j = tid >> 1, half = tid & 1;
        int fo = half * 2;
        if (fo < nval) {
            float2 v = *(const float2*)&res[j * FPB + fo];
            size_t o = ((size_t)bb * NMELS + j) * NFRM + (size_t)(f0 + fo);
            *(float2*)&out[o] = v;     // o is even -> 8B aligned
        }
    }
}

extern "C" void kernel_launch(void* const* d_in, const int* in_sizes, int n_in,
                              void* d_out, int out_size, void* d_ws, size_t ws_size,
                              hipStream_t stream)
{
    const float* wav = (const float*)d_in[0];
    float* out = (float*)d_out;
    fbank_kernel<<<dim3(32 * BPB), dim3(320), 0, stream>>>(wav, out);
}

// Round 2
// 56.813 us; speedup vs baseline: 4.1295x; 4.1295x over previous
//
#include <hip/hip_runtime.h>
#include <math.h>

#ifndef M_PI
#define M_PI 3.14159265358979323846
#endif

#define NWIN   400
#define NSHIFT 160
#define NMELS  80
#define NFRM   998
#define WLEN   160000
#define FPB    4
#define BPB    250          // frame-blocks per batch (249 full + 1 tail of 2)
#define EPSV   1.1920929e-07f

// XOR swizzle on complex (float2) slot index: removes the 16-way bank
// conflict at FFT stage 2 (slot mod 16 would be lane-invariant there).
__device__ __forceinline__ int swz(int s) { return s ^ ((s >> 4) & 15); }

__global__ __launch_bounds__(256)
void fbank_kernel(const float* __restrict__ wav, float* __restrict__ out)
{
    __shared__ __align__(16) float zbf[FPB][512];     // per-wave complex buffer
    __shared__ __align__(16) float pbuf[FPB][256];    // power spectrum
    __shared__ __align__(16) float wbuf[NWIN];        // Povey window (block-shared)
    __shared__ __align__(16) float ubuf[256];         // mel coordinate per bin
    __shared__ __align__(16) float res[NMELS * FPB];  // logmel [mel][frame-slot]

    const int tid  = threadIdx.x;
    const int lane = tid & 63;
    const int wv   = tid >> 6;                 // one wave per frame
    const int bb   = blockIdx.x / BPB;
    const int f0   = (blockIdx.x % BPB) * FPB;
    const bool valid = (f0 + wv) < NFRM;

    const float ML = 1127.0f * logf(1.0f + 20.0f / 700.0f);
    const float MH = 1127.0f * logf(1.0f + 8000.0f / 700.0f);
    const float DD = (MH - ML) / (float)(NMELS + 1);

    // ---- one-time tables (256 threads cover both) ----
    {
        float freq = (float)tid * 31.25f;               // SR/NFFT
        float mel  = 1127.0f * logf(1.0f + freq * (1.0f / 700.0f));
        ubuf[tid]  = (mel - ML) / DD;
        const float CW = (float)(2.0 * M_PI / 399.0);
        float a = fmaxf(0.5f - 0.5f * cosf((float)tid * CW), 0.0f);
        wbuf[tid] = powf(a, 0.85f);
        if (tid < NWIN - 256) {
            int n = tid + 256;
            float a2 = fmaxf(0.5f - 0.5f * cosf((float)n * CW), 0.0f);
            wbuf[n] = powf(a2, 0.85f);
        }
    }
    __syncthreads();

    float*  zf = zbf[wv];
    float2* zc = (float2*)zf;

    // ---- preprocess: de-mean, pre-emphasis, window; pack y[2m],y[2m+1] as z[m] ----
    if (valid) {
        const float* xp = wav + (size_t)bb * WLEN + (size_t)(f0 + wv) * NSHIFT;
        float xv[7];
        #pragma unroll
        for (int t = 0; t < 7; ++t) {
            int n = 64 * t + lane;
            xv[t] = (t < 6 || lane < 16) ? xp[n] : 0.0f;
        }
        float s = xv[0] + xv[1] + xv[2] + xv[3] + xv[4] + xv[5] + xv[6];
        #pragma unroll
        for (int off = 32; off > 0; off >>= 1) s += __shfl_xor(s, off, 64);
        const float mu = s * (1.0f / (float)NWIN);
        #pragma unroll
        for (int t = 0; t < 7; ++t) {
            int n = 64 * t + lane;
            float pm = __shfl_up(xv[t], 1, 64);          // x[n-1] for lane>0
            if (t > 0) {
                float lastv = __shfl(xv[t - 1], 63, 64); // x[64t-1]
                if (lane == 0) pm = lastv;
            } else if (lane == 0) {
                pm = xv[0];                               // ref: prev[0] = x[0]
            }
            float y = 0.0f;
            if (t < 6 || lane < 16)
                y = fmaf(-0.97f, pm - mu, xv[t] - mu) * wbuf[n];
            int s2 = n >> 1;
            zf[(swz(s2) << 1) | (n & 1)] = y;             // n>=400 slots get 0
        }
        // zero-pad z[224..255] (floats 448..511)
        zf[(swz((448 + lane) >> 1) << 1) | (lane & 1)] = 0.0f;
    }

    // ---- 256-point radix-4 DIF FFT, in-place, digit-reversed output ----
    // Wave-private LDS: same-wave DS ordering + compiler lgkmcnt suffice.
    if (valid) {
        #pragma unroll
        for (int st = 0; st < 4; ++st) {
            const int Q = 64 >> (2 * st);                 // L/4
            int j  = lane & (Q - 1);
            int i0 = ((lane & ~(Q - 1)) << 2) + j;        // base + j
            float2 a0 = zc[swz(i0)];
            float2 a1 = zc[swz(i0 + Q)];
            float2 a2 = zc[swz(i0 + 2 * Q)];
            float2 a3 = zc[swz(i0 + 3 * Q)];
            float t0x = a0.x + a2.x, t0y = a0.y + a2.y;
            float t1x = a1.x + a3.x, t1y = a1.y + a3.y;
            float t2x = a0.x - a2.x, t2y = a0.y - a2.y;
            float t3x = a1.x - a3.x, t3y = a1.y - a3.y;
            float b0x = t0x + t1x, b0y = t0y + t1y;       // q=0
            float b2x = t0x - t1x, b2y = t0y - t1y;       // q=2
            float b1x = t2x + t3y, b1y = t2y - t3x;       // q=1: t2 - i*t3
            float b3x = t2x - t3y, b3y = t2y + t3x;       // q=3: t2 + i*t3
            float ang = (float)j * (float)(-M_PI / 2.0 / (double)Q);  // -2*pi*j/L
            float sn, cn;
            __sincosf(ang, &sn, &cn);                     // W1 = (cn, sn)
            float w2x = cn * cn - sn * sn, w2y = 2.0f * cn * sn;      // W1^2
            float w3x = w2x * cn - w2y * sn, w3y = w2x * sn + w2y * cn;
            zc[swz(i0)]         = make_float2(b0x, b0y);
            zc[swz(i0 + Q)]     = make_float2(b1x * cn  - b1y * sn,  b1x * sn  + b1y * cn);
            zc[swz(i0 + 2*Q)]   = make_float2(b2x * w2x - b2y * w2y, b2x * w2y + b2y * w2x);
            zc[swz(i0 + 3*Q)]   = make_float2(b3x * w3x - b3y * w3y, b3x * w3y + b3y * w3x);
        }
    }

    // ---- real-FFT untangle + power: X[k] = E + W512^k * O ----
    if (valid) {
        float th = (float)lane * (float)(-M_PI / 256.0);
        float Wy_, Wx_;
        __sincosf(th, &Wy_, &Wx_);
        const float C8 = 0.70710678f;                     // e^{-i*pi/4} = C8*(1 - i)
        #pragma unroll
        for (int r = 0; r < 4; ++r) {
            int k = lane + 64 * r;
            int m = (256 - k) & 255;
            int rk = ((k & 3) << 6) | (((k >> 2) & 3) << 4) | (((k >> 4) & 3) << 2) | ((k >> 6) & 3);
            int rm = ((m & 3) << 6) | (((m >> 2) & 3) << 4) | (((m >> 4) & 3) << 2) | ((m >> 6) & 3);
            float2 Zk = zc[swz(rk)];
            float2 Zm = zc[swz(rm)];
            float Ex = 0.5f * (Zk.x + Zm.x), Ey = 0.5f * (Zk.y - Zm.y);
            float Ox = 0.5f * (Zk.y + Zm.y), Oy = -0.5f * (Zk.x - Zm.x);
            float Xx = Ex + (Wx_ * Ox - Wy_ * Oy);
            float Xy = Ey + (Wx_ * Oy + Wy_ * Ox);
            pbuf[wv][k] = fmaf(Xx, Xx, Xy * Xy);
            float nWx = C8 * (Wx_ + Wy_);                 // W *= e^{-i*pi/4}
            float nWy = C8 * (Wy_ - Wx_);
            Wx_ = nWx; Wy_ = nWy;
        }
    }

    // ---- mel triangles + log (pbuf is wave-private; no barrier needed) ----
    if (valid) {
        #pragma unroll
        for (int round = 0; round < 2; ++round) {
            int j = lane + 64 * round;
            if (j < NMELS) {
                float mlo  = ML + (float)j * DD;
                float mhi  = ML + (float)(j + 2) * DD;
                float bflo = 22.4f * (expf(mlo * (1.0f / 1127.0f)) - 1.0f); // 700/31.25
                float bfhi = 22.4f * (expf(mhi * (1.0f / 1127.0f)) - 1.0f);
                int blo = max(1,   (int)bflo);
                int bhi = min(255, (int)bfhi + 1);
                float jf = (float)j, jf2 = (float)(j + 2);
                float acc = 0.0f;
                for (int b = blo; b <= bhi; ++b) {
                    float u   = ubuf[b];
                    float wgt = fmaxf(0.0f, fminf(u - jf, jf2 - u));
                    acc = fmaf(wgt, pbuf[wv][b], acc);
                }
                res[j * FPB + wv] = logf(fmaxf(acc, EPSV));
            }
        }
    }
    __syncthreads();

    // ---- transposed output, 8B bursts ----
    const int nval = min(FPB, NFRM - f0);
    if (tid < NMELS) {
        size_t o = ((size_t)bb * NMELS + tid) * NFRM + (size_t)f0;
        *(float2*)&out[o] = make_float2(res[tid * 4 + 0], res[tid * 4 + 1]);
        if (nval == 4)
            *(float2*)&out[o + 2] = make_float2(res[tid * 4 + 2], res[tid * 4 + 3]);
    }
}

extern "C" void kernel_launch(void* const* d_in, const int* in_sizes, int n_in,
                              void* d_out, int out_size, void* d_ws, size_t ws_size,
                              hipStream_t stream)
{
    const float* wav = (const float*)d_in[0];
    float* out = (float*)d_out;
    fbank_kernel<<<dim3(32 * BPB), dim3(256), 0, stream>>>(wav, out);
}

// Round 4
// 47.692 us; speedup vs baseline: 4.9192x; 1.1912x over previous
//
#include <hip/hip_runtime.h>
#include <math.h>

#ifndef M_PI
#define M_PI 3.14159265358979323846
#endif

#define NWIN   400
#define NSHIFT 160
#define NMELS  80
#define NFRM   998
#define WLEN   160000
#define FPB    4
#define BPB    250          // frame-blocks per batch (249 full + 1 tail of 2)
#define EPSV   1.1920929e-07f

// workspace layout (floats)
#define WIN_OFF  0      // [400] Povey window
#define UMEL_OFF 512    // [256] mel coordinate of each bin
#define TWID_OFF 768    // [85*6] per-stage radix-4 twiddles (W1,W2,W3 as x,y)
#define MELB_OFF 1280   // [80*2] int2 (blo,bhi) per mel
#define WS_FLOATS 1440  // 5760 B

// XOR swizzle on complex (float2) slot index: all 4 FFT stages then hit the
// 4-lane-per-bank-pair floor for b64 (verified per-stage on paper).
__device__ __forceinline__ int swz(int s) { return s ^ ((s >> 4) & 15); }

__global__ __launch_bounds__(128)
void setup_kernel(float* __restrict__ ws)
{
    const int gid = blockIdx.x * 128 + threadIdx.x;   // grid 8 x 128
    const double ML = 1127.0 * log(1.0 + 20.0 / 700.0);
    const double MH = 1127.0 * log(1.0 + 8000.0 / 700.0);
    const double DD = (MH - ML) / (double)(NMELS + 1);

    if (gid < NWIN) {
        double a = 0.5 - 0.5 * cos(2.0 * M_PI * (double)gid / 399.0);
        if (a < 0.0) a = 0.0;
        ws[WIN_OFF + gid] = (float)pow(a, 0.85);
    } else if (gid >= 512 && gid < 768) {
        int b = gid - 512;
        double mel = 1127.0 * log(1.0 + (double)b * 31.25 / 700.0);
        ws[UMEL_OFF + b] = (float)((mel - ML) / DD);
    } else if (gid >= 768 && gid < 853) {
        int e = gid - 768, st, j;
        if      (e < 64) { st = 0; j = e; }
        else if (e < 80) { st = 1; j = e - 64; }
        else if (e < 84) { st = 2; j = e - 80; }
        else             { st = 3; j = 0; }
        int Q = 64 >> (2 * st);
        double ang = -M_PI * (double)j / (2.0 * (double)Q);   // -2*pi*j/(4Q)
        float* t = ws + TWID_OFF + e * 6;
        t[0] = (float)cos(ang);       t[1] = (float)sin(ang);
        t[2] = (float)cos(2.0 * ang); t[3] = (float)sin(2.0 * ang);
        t[4] = (float)cos(3.0 * ang); t[5] = (float)sin(3.0 * ang);
    } else if (gid >= 896 && gid < 896 + NMELS) {
        int j = gid - 896;
        double mlo = ML + (double)j * DD;
        double mhi = ML + (double)(j + 2) * DD;
        double flo = 700.0 * (exp(mlo / 1127.0) - 1.0);
        double fhi = 700.0 * (exp(mhi / 1127.0) - 1.0);
        int blo = max(1,   (int)(flo / 31.25));        // +-1 slack is weight-clamped
        int bhi = min(255, (int)(fhi / 31.25) + 1);
        ((int2*)(ws + MELB_OFF))[j] = make_int2(blo, bhi);
    }
}

template<bool USE_TAB>
__global__ __launch_bounds__(256)
void fbank_kernel(const float* __restrict__ wav, float* __restrict__ out,
                  const float* __restrict__ ws)
{
    __shared__ __align__(16) float zbf[FPB][512];     // per-wave complex buffer
    __shared__ __align__(16) float pbuf[FPB][256];    // power spectrum
    __shared__ __align__(16) float wbuf[NWIN];        // Povey window
    __shared__ __align__(16) float ubuf[256];         // mel coordinate per bin
    __shared__ __align__(16) float res[NMELS * FPB];  // logmel [mel][frame-slot]

    const int tid  = threadIdx.x;
    const int lane = tid & 63;
    const int wv   = tid >> 6;                 // one wave per frame
    const int bb   = blockIdx.x / BPB;
    const int f0   = (blockIdx.x % BPB) * FPB;
    const bool valid = (f0 + wv) < NFRM;

    const float ML = 1127.0f * logf(1.0f + 20.0f / 700.0f);
    const float MH = 1127.0f * logf(1.0f + 8000.0f / 700.0f);
    const float DD = (MH - ML) / (float)(NMELS + 1);

    // ---- tables: stage from workspace, or (fallback) fast-intrinsic build ----
    if constexpr (USE_TAB) {
        if (tid < 256)  ubuf[tid] = ws[UMEL_OFF + tid];
        wbuf[tid] = ws[WIN_OFF + tid];
        if (tid < NWIN - 256) wbuf[tid + 256] = ws[WIN_OFF + 256 + tid];
    } else {
        float freq = (float)tid * 31.25f;
        ubuf[tid] = (1127.0f * __logf(1.0f + freq * (1.0f / 700.0f)) - ML) / DD;
        const float CW = (float)(2.0 * M_PI / 399.0);
        float a = fmaxf(0.5f - 0.5f * __cosf((float)tid * CW), 0.0f);
        wbuf[tid] = __powf(a, 0.85f);                      // a=0 -> 0 ok
        if (tid < NWIN - 256) {
            int n = tid + 256;
            float a2 = fmaxf(0.5f - 0.5f * __cosf((float)n * CW), 0.0f);
            wbuf[n] = __powf(a2, 0.85f);
        }
    }
    __syncthreads();

    float*  zf = zbf[wv];
    float2* zc = (float2*)zf;

    // ---- preprocess: de-mean, pre-emphasis, window; pack y[2m],y[2m+1] as z[m] ----
    if (valid) {
        const float* xp = wav + (size_t)bb * WLEN + (size_t)(f0 + wv) * NSHIFT;
        float xv[7];
        #pragma unroll
        for (int t = 0; t < 7; ++t) {
            int n = 64 * t + lane;
            xv[t] = (t < 6 || lane < 16) ? xp[n] : 0.0f;
        }
        float s = xv[0] + xv[1] + xv[2] + xv[3] + xv[4] + xv[5] + xv[6];
        #pragma unroll
        for (int off = 32; off > 0; off >>= 1) s += __shfl_xor(s, off, 64);
        const float mu = s * (1.0f / (float)NWIN);
        #pragma unroll
        for (int t = 0; t < 7; ++t) {
            int n = 64 * t + lane;
            float pm = __shfl_up(xv[t], 1, 64);          // x[n-1] for lane>0
            if (t > 0) {
                float lastv = __shfl(xv[t - 1], 63, 64); // x[64t-1]
                if (lane == 0) pm = lastv;
            } else if (lane == 0) {
                pm = xv[0];                               // ref: prev[0] = x[0]
            }
            float y = 0.0f;
            if (t < 6 || lane < 16)
                y = fmaf(-0.97f, pm - mu, xv[t] - mu) * wbuf[n];
            int s2 = n >> 1;
            zf[(swz(s2) << 1) | (n & 1)] = y;             // n>=400 slots get 0
        }
        // zero-pad z[224..255] (floats 448..511)
        zf[(swz((448 + lane) >> 1) << 1) | (lane & 1)] = 0.0f;
    }

    // ---- 256-point radix-4 DIF FFT, in-place, digit-reversed output ----
    // Wave-private LDS: same-wave DS ordering + compiler lgkmcnt suffice.
    if (valid) {
        #pragma unroll
        for (int st = 0; st < 4; ++st) {
            const int Q = 64 >> (2 * st);                 // L/4
            int j  = lane & (Q - 1);
            int i0 = ((lane & ~(Q - 1)) << 2) + j;        // base + j
            float2 a0 = zc[swz(i0)];
            float2 a1 = zc[swz(i0 + Q)];
            float2 a2 = zc[swz(i0 + 2 * Q)];
            float2 a3 = zc[swz(i0 + 3 * Q)];
            float t0x = a0.x + a2.x, t0y = a0.y + a2.y;
            float t1x = a1.x + a3.x, t1y = a1.y + a3.y;
            float t2x = a0.x - a2.x, t2y = a0.y - a2.y;
            float t3x = a1.x - a3.x, t3y = a1.y - a3.y;
            float b0x = t0x + t1x, b0y = t0y + t1y;       // q=0
            float b2x = t0x - t1x, b2y = t0y - t1y;       // q=2
            float b1x = t2x + t3y, b1y = t2y - t3x;       // q=1: t2 - i*t3
            float b3x = t2x - t3y, b3y = t2y + t3x;       // q=3: t2 + i*t3
            float cn, sn, w2x, w2y, w3x, w3y;
            if constexpr (USE_TAB) {
                constexpr int TOFF[4] = {0, 64, 80, 84};
                const float* tw = ws + TWID_OFF + (TOFF[st] + j) * 6;
                cn = tw[0]; sn = tw[1]; w2x = tw[2]; w2y = tw[3]; w3x = tw[4]; w3y = tw[5];
            } else {
                float ang = (float)j * (float)(-M_PI / 2.0 / (double)Q);
                __sincosf(ang, &sn, &cn);
                w2x = cn * cn - sn * sn; w2y = 2.0f * cn * sn;
                w3x = w2x * cn - w2y * sn; w3y = w2x * sn + w2y * cn;
            }
            zc[swz(i0)]       = make_float2(b0x, b0y);
            zc[swz(i0 + Q)]   = make_float2(fmaf(b1x, cn,  -b1y * sn),  fmaf(b1x, sn,  b1y * cn));
            zc[swz(i0 + 2*Q)] = make_float2(fmaf(b2x, w2x, -b2y * w2y), fmaf(b2x, w2y, b2y * w2x));
            zc[swz(i0 + 3*Q)] = make_float2(fmaf(b3x, w3x, -b3y * w3y), fmaf(b3x, w3y, b3y * w3x));
        }
    }

    // ---- real-FFT untangle + power: X[k] = E + W512^k * O ----
    if (valid) {
        float th = (float)lane * (float)(-M_PI / 256.0);
        float Wy_, Wx_;
        __sincosf(th, &Wy_, &Wx_);
        const float C8 = 0.70710678f;                     // e^{-i*pi/4} = C8*(1 - i)
        #pragma unroll
        for (int r = 0; r < 4; ++r) {
            int k = lane + 64 * r;
            int m = (256 - k) & 255;
            int rk = ((k & 3) << 6) | (((k >> 2) & 3) << 4) | (((k >> 4) & 3) << 2) | ((k >> 6) & 3);
            int rm = ((m & 3) << 6) | (((m >> 2) & 3) << 4) | (((m >> 4) & 3) << 2) | ((m >> 6) & 3);
            float2 Zk = zc[swz(rk)];
            float2 Zm = zc[swz(rm)];
            float Ex = 0.5f * (Zk.x + Zm.x), Ey = 0.5f * (Zk.y - Zm.y);
            float Ox = 0.5f * (Zk.y + Zm.y), Oy = -0.5f * (Zk.x - Zm.x);
            float Xx = Ex + (Wx_ * Ox - Wy_ * Oy);
            float Xy = Ey + (Wx_ * Oy + Wy_ * Ox);
            pbuf[wv][k] = fmaf(Xx, Xx, Xy * Xy);
            float nWx = C8 * (Wx_ + Wy_);                 // W *= e^{-i*pi/4}
            float nWy = C8 * (Wy_ - Wx_);
            Wx_ = nWx; Wy_ = nWy;
        }
    }

    // ---- mel triangles + log (pbuf is wave-private; no barrier needed) ----
    if (valid) {
        #pragma unroll
        for (int round = 0; round < 2; ++round) {
            int j = lane + 64 * round;
            if (j < NMELS) {
                int blo, bhi;
                if constexpr (USE_TAB) {
                    int2 bnd = ((const int2*)(ws + MELB_OFF))[j];
                    blo = bnd.x; bhi = bnd.y;
                } else {
                    float mlo  = ML + (float)j * DD;
                    float mhi  = ML + (float)(j + 2) * DD;
                    float bflo = 22.4f * (__expf(mlo * (1.0f / 1127.0f)) - 1.0f);
                    float bfhi = 22.4f * (__expf(mhi * (1.0f / 1127.0f)) - 1.0f);
                    blo = max(1,   (int)bflo);
                    bhi = min(255, (int)bfhi + 1);
                }
                float jf = (float)j, jf2 = (float)(j + 2);
                float acc = 0.0f;
                for (int b = blo; b <= bhi; ++b) {
                    float u   = ubuf[b];
                    float wgt = fmaxf(0.0f, fminf(u - jf, jf2 - u));
                    acc = fmaf(wgt, pbuf[wv][b], acc);
                }
                res[j * FPB + wv] = logf(fmaxf(acc, EPSV));
            }
        }
    }
    __syncthreads();

    // ---- transposed output, 8B bursts ----
    const int nval = min(FPB, NFRM - f0);
    if (tid < NMELS) {
        size_t o = ((size_t)bb * NMELS + tid) * NFRM + (size_t)f0;
        *(float2*)&out[o] = make_float2(res[tid * 4 + 0], res[tid * 4 + 1]);
        if (nval == 4)
            *(float2*)&out[o + 2] = make_float2(res[tid * 4 + 2], res[tid * 4 + 3]);
    }
}

extern "C" void kernel_launch(void* const* d_in, const int* in_sizes, int n_in,
                              void* d_out, int out_size, void* d_ws, size_t ws_size,
                              hipStream_t stream)
{
    const float* wav = (const float*)d_in[0];
    float* out = (float*)d_out;
    float* ws  = (float*)d_ws;
    if (ws != nullptr && ws_size >= WS_FLOATS * sizeof(float)) {
        setup_kernel<<<dim3(8), dim3(128), 0, stream>>>(ws);
        fbank_kernel<true><<<dim3(32 * BPB), dim3(256), 0, stream>>>(wav, out, ws);
    } else {
        fbank_kernel<false><<<dim3(32 * BPB), dim3(256), 0, stream>>>(wav, out, ws);
    }
}